// Round 2
// baseline (268.625 us; speedup 1.0000x reference)
//
#include <hip/hip_runtime.h>
#include <hip/hip_bf16.h>

#define B_ 8
#define D_ 128
#define S_ 4096

typedef short short8 __attribute__((ext_vector_type(8)));
typedef float f32x4  __attribute__((ext_vector_type(4)));
typedef float f32x16 __attribute__((ext_vector_type(16)));
typedef unsigned int uint;
typedef uint uint4v __attribute__((ext_vector_type(4)));

#define EXP2F(x) exp2f(x)

__device__ __forceinline__ short f2bf(float f) {
    __hip_bfloat16 h = __float2bfloat16(f);
    return *reinterpret_cast<short*>(&h);
}

// pack two f32 -> one u32 of 2 bf16 (elem0 = lo word)
__device__ __forceinline__ uint cvtpk(float lo, float hi) {
    uint r;
    asm("v_cvt_pk_bf16_f32 %0, %1, %2" : "=v"(r) : "v"(lo), "v"(hi));
    return r;
}

// async global->LDS DMA, 16B/lane; LDS dest = wave-uniform base + lane*16
__device__ __forceinline__ void gload16(const void* g, void* l) {
    __builtin_amdgcn_global_load_lds(
        (const __attribute__((address_space(1))) void*)g,
        (__attribute__((address_space(3))) void*)l, 16, 0, 0);
}

// ---------------------------------------------------------------------------
// Kernel 0: pack Wq/Wk/Wv into bf16 MFMA fragments (16x16x32 layout for qkv).
// ---------------------------------------------------------------------------
__global__ __launch_bounds__(256) void wpack_kernel(
    const float* __restrict__ Wq, const float* __restrict__ Wk,
    const float* __restrict__ Wv, short* __restrict__ Wf)
{
    int g = blockIdx.x * 256 + threadIdx.x;      // 0..6143
    int lane = g & 63, kc = (g >> 6) & 3, n = (g >> 8) & 7, wm = g >> 11;
    const float* W = (wm == 0) ? Wq : (wm == 1) ? Wk : Wv;
    int row = n * 16 + (lane & 15);
    int col = kc * 32 + (lane >> 4) * 8;
    short8 o;
    #pragma unroll
    for (int j = 0; j < 8; ++j) o[j] = f2bf(W[row * 128 + col + j]);
    *((short8*)Wf + g) = o;
}

// ---------------------------------------------------------------------------
// Kernel 1: QKV projection via bf16 MFMA (16x16x32), unchanged.
// Q: (B,S,D) bf16 scaled by log2(e)/sqrt(D). K: (B,S,D). V: (B,D,S).
// ---------------------------------------------------------------------------
__global__ __launch_bounds__(256) void qkv_kernel(
    const float* __restrict__ x, const short* __restrict__ Wf,
    const float* __restrict__ bq, const float* __restrict__ bk,
    const float* __restrict__ bv,
    short* __restrict__ Qo, short* __restrict__ Ko, short* __restrict__ Vo)
{
    __shared__ float xt[64 * 132];
    const int b  = blockIdx.y;
    const int s0 = blockIdx.x * 64;
    const int t  = threadIdx.x;
    const int w    = t >> 6;
    const int lane = t & 63;
    const int lr   = lane & 15;
    const int lg   = lane >> 4;

    const float* xb = x + (size_t)b * D_ * S_;
    #pragma unroll
    for (int it = 0; it < 32; ++it) {
        int d = it * 4 + (t >> 6);
        int s = t & 63;
        xt[s * 132 + d] = xb[(size_t)d * S_ + s0 + s];
    }
    __syncthreads();

    short8 xtf[4];
    {
        const float* base = &xt[(w * 16 + lr) * 132 + lg * 8];
        #pragma unroll
        for (int kc = 0; kc < 4; ++kc) {
            float4 a = *(const float4*)(base + kc * 32);
            float4 c = *(const float4*)(base + kc * 32 + 4);
            short8 f;
            f[0] = f2bf(a.x); f[1] = f2bf(a.y); f[2] = f2bf(a.z); f[3] = f2bf(a.w);
            f[4] = f2bf(c.x); f[5] = f2bf(c.y); f[6] = f2bf(c.z); f[7] = f2bf(c.w);
            xtf[kc] = f;
        }
    }

    const float qs = 0.08838834764831845f * 1.4426950408889634f;
    const short8* W8 = (const short8*)Wf;
    const size_t bSD = (size_t)b * S_ * D_;
    const size_t bDS = (size_t)b * D_ * S_;

    #pragma unroll
    for (int n = 0; n < 8; ++n) {
        f32x4 aq = (f32x4){0.f, 0.f, 0.f, 0.f};
        f32x4 ak = (f32x4){0.f, 0.f, 0.f, 0.f};
        f32x4 av = (f32x4){0.f, 0.f, 0.f, 0.f};
        #pragma unroll
        for (int kc = 0; kc < 4; ++kc) {
            short8 wq = W8[(      n * 4 + kc) * 64 + lane];
            short8 wk = W8[(32  + n * 4 + kc) * 64 + lane];
            short8 wv = W8[(64  + n * 4 + kc) * 64 + lane];
            aq = __builtin_amdgcn_mfma_f32_16x16x32_bf16(xtf[kc], wq, aq, 0, 0, 0);
            ak = __builtin_amdgcn_mfma_f32_16x16x32_bf16(xtf[kc], wk, ak, 0, 0, 0);
            av = __builtin_amdgcn_mfma_f32_16x16x32_bf16(wv, xtf[kc], av, 0, 0, 0);
        }
        int e = n * 16 + lr;
        float bqe = bq[e], bke = bk[e];
        #pragma unroll
        for (int r = 0; r < 4; ++r) {
            size_t off = (bSD + (size_t)(s0 + w * 16 + lg * 4 + r) * D_) + e;
            Qo[off] = f2bf((aq[r] + bqe) * qs);
            Ko[off] = f2bf(ak[r] + bke);
        }
        #pragma unroll
        for (int r = 0; r < 4; ++r) {
            int ev = n * 16 + lg * 4 + r;
            Vo[bDS + (size_t)ev * S_ + s0 + w * 16 + lr] = f2bf(av[r] + bv[ev]);
        }
    }
}

// ---------------------------------------------------------------------------
// Kernel 2: flash attention, occupancy-doubled vs 128KB-LDS version.
// 512 blocks x 512 threads: 8 waves = 4 kv-quarters (1024 kv each) x 2
// q-subwaves (64 q/block). KVBLK=32. K staged via global_load_lds DMA
// (double-buffered, XOR-swizzled content), V fragments read DIRECT from
// global (L2-resident: one batch per XCD via lin&7 swizzle).
// LDS 66KB -> 2 blocks/CU (launch_bounds(512,4) caps regs at 128/wave).
// Cross-half (hi) reductions use __shfl_xor(.,32): permlane32_swap with two
// identical-valued operands gets register-coalesced into an in-place swap
// (WRONG) -- only the P-pack uses permlane (distinct defs, safe).
// C/D layout (m74/m101): col=lane&31, row=(reg&3)+8*(reg>>2)+4*(lane>>5).
// ---------------------------------------------------------------------------
__global__ __launch_bounds__(512, 4) void attn_kernel(
    const short* __restrict__ Q, const short* __restrict__ K,
    const short* __restrict__ Vt, const float* __restrict__ x,
    float* __restrict__ out)
{
    extern __shared__ __align__(16) char smem[];   // 67584 B
    const int lin = blockIdx.x;
    const int b   = lin & 7;            // XCD swizzle: one b per XCD
    const int q0  = (lin >> 3) * 64;
    const int t    = threadIdx.x;
    const int w    = t >> 6;
    const int lane = t & 63;
    const int q    = lane & 31;         // this lane's q column
    const int hi   = lane >> 5;
    const int qr   = w >> 1;            // kv quarter: rows qr*1024 .. +1023
    const int ww   = w & 1;             // q sub-block (q0 + ww*32 ..)

    const size_t bSD = (size_t)b * S_ * D_;

    // Q fragments: qf[c][j] = Q[q0+ww*32+q][c*16 + hi*8 + j]
    short8 qf[8];
    {
        const short* Qrow = Q + bSD + (size_t)(q0 + ww * 32 + q) * D_ + hi * 8;
        #pragma unroll
        for (int c = 0; c < 8; ++c)
            qf[c] = *(const short8*)(Qrow + c * 16);
    }

    f32x16 o[4];
    #pragma unroll
    for (int dt = 0; dt < 4; ++dt)
        #pragma unroll
        for (int i = 0; i < 16; ++i) o[dt][i] = 0.f;
    float m = -1e30f, lsum = 0.f;

    const short* Kb = K + bSD;
    const short* Vb = Vt + (size_t)b * D_ * S_;
    const int kvbase = qr * 1024;

    // DMA-stage one 32-kv K tile of this wave's quarter into buffer `buf`.
    // LDS dest linear; global src pre-swizzled: phys 16B-chunk c of row r
    // holds logical chunk c^(r&7).
    auto stage = [&](int kt, int buf) {
        const short* Kg = Kb + (size_t)(kvbase + kt * 32) * D_;
        char* Kd = smem + buf * 32768 + qr * 8192;
        #pragma unroll
        for (int i = 0; i < 4; ++i) {
            int ki = ww * 4 + i;                 // 1KB chunk: rows 4ki..4ki+3
            int r  = ki * 4 + (lane >> 4);
            gload16(Kg + r * D_ + (((lane & 15) ^ (r & 7)) * 8), Kd + ki * 1024);
        }
    };

    stage(0, 0);
    __syncthreads();                 // drains vmcnt -> buf0 ready
    int cur = 0;

    for (int kt = 0; kt < 32; ++kt) {
        if (kt + 1 < 32) stage(kt + 1, cur ^ 1);   // DMA overlaps compute

        const char* Kh = smem + cur * 32768 + qr * 8192;

        // ---- S^T = K Q^T : acc[r] = S[k = (r&3)+8*(r>>2)+4*hi][q] ----
        f32x16 acc;
        #pragma unroll
        for (int i = 0; i < 16; ++i) acc[i] = 0.f;
        __builtin_amdgcn_s_setprio(1);
        #pragma unroll
        for (int c = 0; c < 8; ++c) {
            short8 kf = *(const short8*)(Kh + q * 256
                          + (((c * 2 + hi) ^ (q & 7)) * 16));
            acc = __builtin_amdgcn_mfma_f32_32x32x16_bf16(kf, qf[c], acc, 0, 0, 0);
        }
        __builtin_amdgcn_s_setprio(0);

        // ---- lane-local online softmax (exp2 domain), defer-max (T13) ----
        float t0 = fmaxf(acc[0],  acc[1]),  t1 = fmaxf(acc[2],  acc[3]);
        float t2 = fmaxf(acc[4],  acc[5]),  t3 = fmaxf(acc[6],  acc[7]);
        float t4 = fmaxf(acc[8],  acc[9]),  t5 = fmaxf(acc[10], acc[11]);
        float t6 = fmaxf(acc[12], acc[13]), t7 = fmaxf(acc[14], acc[15]);
        float ta = fmaxf(fmaxf(t0, t1), t2);
        float tb = fmaxf(fmaxf(t3, t4), t5);
        float tc = fmaxf(t6, t7);
        float tm = fmaxf(fmaxf(ta, tb), tc);
        tm = fmaxf(tm, __shfl_xor(tm, 32));
        if (!__all(tm <= m + 8.f)) {
            float mn   = fmaxf(m, tm);
            float corr = EXP2F(m - mn);
            m = mn; lsum *= corr;
            #pragma unroll
            for (int dt = 0; dt < 4; ++dt)
                #pragma unroll
                for (int r = 0; r < 16; ++r) o[dt][r] *= corr;
        }
        #pragma unroll
        for (int r = 0; r < 16; ++r) acc[r] = EXP2F(acc[r] - m);
        float s0 = (acc[0] + acc[1]) + (acc[2] + acc[3]);
        float s1 = (acc[4] + acc[5]) + (acc[6] + acc[7]);
        float s2 = (acc[8] + acc[9]) + (acc[10] + acc[11]);
        float s3 = (acc[12] + acc[13]) + (acc[14] + acc[15]);
        float ps = (s0 + s1) + (s2 + s3);
        ps += __shfl_xor(ps, 32);
        lsum += ps;

        // ---- P -> bf16 PV B-fragments, in-register via permlane32_swap ----
        // W0..W3 are distinct SSA defs -> no register coalescing hazard.
        short8 pf[2];
        #pragma unroll
        for (int kc = 0; kc < 2; ++kc) {
            int c1 = kc * 8;
            uint W0 = cvtpk(acc[c1 + 0], acc[c1 + 1]);   // k: 4hi+{0,1}
            uint W1 = cvtpk(acc[c1 + 2], acc[c1 + 3]);   // k: 4hi+{2,3}
            uint W2 = cvtpk(acc[c1 + 4], acc[c1 + 5]);   // k: 8+4hi+{0,1}
            uint W3 = cvtpk(acc[c1 + 6], acc[c1 + 7]);   // k: 8+4hi+{2,3}
            asm("v_permlane32_swap_b32 %0, %1" : "+v"(W0), "+v"(W2));
            asm("v_permlane32_swap_b32 %0, %1" : "+v"(W1), "+v"(W3));
            uint4v pw;
            pw.x = W0;   // k 8hi+{0,1}
            pw.y = W1;   // k 8hi+{2,3}
            pw.z = W2;   // k 8hi+{4,5}
            pw.w = W3;   // k 8hi+{6,7}
            pf[kc] = *reinterpret_cast<short8*>(&pw);
        }

        // ---- O^T += V^T P^T  (V fragments direct from global / L2) ----
        const short* Vg = Vb + kvbase + kt * 32 + hi * 8;
        __builtin_amdgcn_s_setprio(1);
        #pragma unroll
        for (int kc = 0; kc < 2; ++kc)
            #pragma unroll
            for (int dt = 0; dt < 4; ++dt) {
                short8 vf = *(const short8*)(Vg + (size_t)(dt * 32 + q) * S_
                                             + kc * 16);
                o[dt] = __builtin_amdgcn_mfma_f32_32x32x16_bf16(vf, pf[kc], o[dt], 0, 0, 0);
            }
        __builtin_amdgcn_s_setprio(0);

        __syncthreads();     // reads of buf[cur] done + DMA into buf[cur^1] drained
        cur ^= 1;
    }

    // ---- cross-quarter merge (tree through LDS, reusing dead K buffers) ----
    float2* ml = (float2*)(smem + 65536);
    if (hi == 0) {
        float2 v2; v2.x = m; v2.y = lsum;
        ml[(ww * 4 + qr) * 32 + q] = v2;
    }
    __syncthreads();
    float M = -1e30f;
    float mx[4], ly[4];
    #pragma unroll
    for (int i = 0; i < 4; ++i) {
        float2 v2 = ml[(ww * 4 + i) * 32 + q];
        mx[i] = v2.x; ly[i] = v2.y;
        M = fmaxf(M, mx[i]);
    }
    float L = 0.f;
    #pragma unroll
    for (int i = 0; i < 4; ++i) L += ly[i] * EXP2F(mx[i] - M);
    float cf = EXP2F(m - M);
    #pragma unroll
    for (int dt = 0; dt < 4; ++dt)
        #pragma unroll
        for (int r = 0; r < 16; ++r) o[dt][r] *= cf;

    float* buf01 = (float*)smem + ww * 4096;            // 16KB per ww
    float* buf23 = (float*)smem + 8192 + ww * 4096;
    if (qr == 1 || qr == 3) {
        float* bw = (qr == 1) ? buf01 : buf23;
        #pragma unroll
        for (int dt = 0; dt < 4; ++dt)
            #pragma unroll
            for (int r = 0; r < 16; ++r) {
                int dl = dt * 32 + (r & 3) + 8 * (r >> 2) + 4 * hi;
                bw[dl * 32 + q] = o[dt][r];
            }
    }
    __syncthreads();
    if (qr == 0) {
        #pragma unroll
        for (int dt = 0; dt < 4; ++dt)
            #pragma unroll
            for (int r = 0; r < 16; ++r) {
                int dl = dt * 32 + (r & 3) + 8 * (r >> 2) + 4 * hi;
                o[dt][r] += buf01[dl * 32 + q];
            }
    } else if (qr == 2) {
        #pragma unroll
        for (int dt = 0; dt < 4; ++dt)
            #pragma unroll
            for (int r = 0; r < 16; ++r) {
                int dl = dt * 32 + (r & 3) + 8 * (r >> 2) + 4 * hi;
                o[dt][r] += buf23[dl * 32 + q];
                buf23[dl * 32 + q] = o[dt][r];   // own index: no cross-lane hazard
            }
    }
    __syncthreads();
    if (qr == 0) {
        float invL = 1.0f / L;
        const float* xb = x   + (size_t)b * D_ * S_;
        float*       ob = out + (size_t)b * D_ * S_;
        int s = q0 + ww * 32 + q;
        #pragma unroll
        for (int dt = 0; dt < 4; ++dt)
            #pragma unroll
            for (int r = 0; r < 16; ++r) {
                int dl = dt * 32 + (r & 3) + 8 * (r >> 2) + 4 * hi;
                float val = (o[dt][r] + buf23[dl * 32 + q]) * invL;
                size_t g = (size_t)dl * S_ + s;
                ob[g] = xb[g] + val;
            }
    }
}

extern "C" void kernel_launch(void* const* d_in, const int* in_sizes, int n_in,
                              void* d_out, int out_size, void* d_ws, size_t ws_size,
                              hipStream_t stream) {
    const float* x  = (const float*)d_in[0];
    const float* Wq = (const float*)d_in[1];
    const float* bq = (const float*)d_in[2];
    const float* Wk = (const float*)d_in[3];
    const float* bk = (const float*)d_in[4];
    const float* Wv = (const float*)d_in[5];
    const float* bv = (const float*)d_in[6];
    float* out = (float*)d_out;

    size_t n = (size_t)B_ * S_ * D_;
    short* Qw = (short*)d_ws;
    short* Kw = Qw + n;
    short* Vw = Kw + n;
    short* Wf = (short*)d_out;   // scratch at head of d_out; fully overwritten

    wpack_kernel<<<24, 256, 0, stream>>>(Wq, Wk, Wv, Wf);

    dim3 grid(S_ / 64, B_);
    qkv_kernel<<<grid, 256, 0, stream>>>(x, Wf, bq, bk, bv, Qw, Kw, Vw);

    int smemB = 67584;
    (void)hipFuncSetAttribute((const void*)attn_kernel,
                              hipFuncAttributeMaxDynamicSharedMemorySize, smemB);
    attn_kernel<<<512, 512, smemB, stream>>>(Qw, Kw, Vw, x, out);
}

// Round 3
// 214.886 us; speedup vs baseline: 1.2501x; 1.2501x over previous
//
#include <hip/hip_runtime.h>
#include <hip/hip_bf16.h>

#define B_ 8
#define D_ 128
#define S_ 4096

typedef short short8 __attribute__((ext_vector_type(8)));
typedef float f32x4  __attribute__((ext_vector_type(4)));
typedef float f32x16 __attribute__((ext_vector_type(16)));
typedef unsigned int uint;
typedef uint uint4v __attribute__((ext_vector_type(4)));

#define EXP2F(x) exp2f(x)

__device__ __forceinline__ short f2bf(float f) {
    __hip_bfloat16 h = __float2bfloat16(f);
    return *reinterpret_cast<short*>(&h);
}

// pack two f32 -> one u32 of 2 bf16 (elem0 = lo word)
__device__ __forceinline__ uint cvtpk(float lo, float hi) {
    uint r;
    asm("v_cvt_pk_bf16_f32 %0, %1, %2" : "=v"(r) : "v"(lo), "v"(hi));
    return r;
}

// async global->LDS DMA, 16B/lane; LDS dest = wave-uniform base + lane*16
__device__ __forceinline__ void gload16(const void* g, void* l) {
    __builtin_amdgcn_global_load_lds(
        (const __attribute__((address_space(1))) void*)g,
        (__attribute__((address_space(3))) void*)l, 16, 0, 0);
}

// ---------------------------------------------------------------------------
// Kernel 0: pack Wq/Wk/Wv into bf16 MFMA fragments (16x16x32 layout for qkv).
// ---------------------------------------------------------------------------
__global__ __launch_bounds__(256) void wpack_kernel(
    const float* __restrict__ Wq, const float* __restrict__ Wk,
    const float* __restrict__ Wv, short* __restrict__ Wf)
{
    int g = blockIdx.x * 256 + threadIdx.x;      // 0..6143
    int lane = g & 63, kc = (g >> 6) & 3, n = (g >> 8) & 7, wm = g >> 11;
    const float* W = (wm == 0) ? Wq : (wm == 1) ? Wk : Wv;
    int row = n * 16 + (lane & 15);
    int col = kc * 32 + (lane >> 4) * 8;
    short8 o;
    #pragma unroll
    for (int j = 0; j < 8; ++j) o[j] = f2bf(W[row * 128 + col + j]);
    *((short8*)Wf + g) = o;
}

// ---------------------------------------------------------------------------
// Kernel 1: QKV projection via bf16 MFMA (16x16x32), unchanged.
// Q: (B,S,D) bf16 scaled by log2(e)/sqrt(D). K: (B,S,D). V: (B,D,S).
// ---------------------------------------------------------------------------
__global__ __launch_bounds__(256) void qkv_kernel(
    const float* __restrict__ x, const short* __restrict__ Wf,
    const float* __restrict__ bq, const float* __restrict__ bk,
    const float* __restrict__ bv,
    short* __restrict__ Qo, short* __restrict__ Ko, short* __restrict__ Vo)
{
    __shared__ float xt[64 * 132];
    const int b  = blockIdx.y;
    const int s0 = blockIdx.x * 64;
    const int t  = threadIdx.x;
    const int w    = t >> 6;
    const int lane = t & 63;
    const int lr   = lane & 15;
    const int lg   = lane >> 4;

    const float* xb = x + (size_t)b * D_ * S_;
    #pragma unroll
    for (int it = 0; it < 32; ++it) {
        int d = it * 4 + (t >> 6);
        int s = t & 63;
        xt[s * 132 + d] = xb[(size_t)d * S_ + s0 + s];
    }
    __syncthreads();

    short8 xtf[4];
    {
        const float* base = &xt[(w * 16 + lr) * 132 + lg * 8];
        #pragma unroll
        for (int kc = 0; kc < 4; ++kc) {
            float4 a = *(const float4*)(base + kc * 32);
            float4 c = *(const float4*)(base + kc * 32 + 4);
            short8 f;
            f[0] = f2bf(a.x); f[1] = f2bf(a.y); f[2] = f2bf(a.z); f[3] = f2bf(a.w);
            f[4] = f2bf(c.x); f[5] = f2bf(c.y); f[6] = f2bf(c.z); f[7] = f2bf(c.w);
            xtf[kc] = f;
        }
    }

    const float qs = 0.08838834764831845f * 1.4426950408889634f;
    const short8* W8 = (const short8*)Wf;
    const size_t bSD = (size_t)b * S_ * D_;
    const size_t bDS = (size_t)b * D_ * S_;

    #pragma unroll
    for (int n = 0; n < 8; ++n) {
        f32x4 aq = (f32x4){0.f, 0.f, 0.f, 0.f};
        f32x4 ak = (f32x4){0.f, 0.f, 0.f, 0.f};
        f32x4 av = (f32x4){0.f, 0.f, 0.f, 0.f};
        #pragma unroll
        for (int kc = 0; kc < 4; ++kc) {
            short8 wq = W8[(      n * 4 + kc) * 64 + lane];
            short8 wk = W8[(32  + n * 4 + kc) * 64 + lane];
            short8 wv = W8[(64  + n * 4 + kc) * 64 + lane];
            aq = __builtin_amdgcn_mfma_f32_16x16x32_bf16(xtf[kc], wq, aq, 0, 0, 0);
            ak = __builtin_amdgcn_mfma_f32_16x16x32_bf16(xtf[kc], wk, ak, 0, 0, 0);
            av = __builtin_amdgcn_mfma_f32_16x16x32_bf16(wv, xtf[kc], av, 0, 0, 0);
        }
        int e = n * 16 + lr;
        float bqe = bq[e], bke = bk[e];
        #pragma unroll
        for (int r = 0; r < 4; ++r) {
            size_t off = (bSD + (size_t)(s0 + w * 16 + lg * 4 + r) * D_) + e;
            Qo[off] = f2bf((aq[r] + bqe) * qs);
            Ko[off] = f2bf(ak[r] + bke);
        }
        #pragma unroll
        for (int r = 0; r < 4; ++r) {
            int ev = n * 16 + lg * 4 + r;
            Vo[bDS + (size_t)ev * S_ + s0 + w * 16 + lr] = f2bf(av[r] + bv[ev]);
        }
    }
}

// ---------------------------------------------------------------------------
// Kernel 2: flash attention, BARRIER-FREE main loop.
// 256 blocks x 512 threads: 8 waves = 2 kv-halves (2048 kv) x 4 q-strips
// (128 q/block). Each wave PRIVATELY stages its own 32-kv K tile via
// global_load_lds (own 16KB double-buffered LDS region; 8 waves = 128KB),
// synced by its own s_waitcnt vmcnt(0) -- NO __syncthreads in the loop.
// Waves drift out of phase so softmax VALU of one wave hides the QK MFMA
// chain of its SIMD partner (m191 structure where setprio pays).
// V fragments direct from global (L2-resident; one batch per XCD, lin&7).
// launch_bounds(512,2): 256 unified VGPR+AGPR per wave -- NO spill (R2's
// failure mode: (512,4) = 128-reg budget vs ~190 live regs -> scratch).
// C/D layout (m74/m101): col=lane&31, row=(reg&3)+8*(reg>>2)+4*(lane>>5).
// ---------------------------------------------------------------------------
__global__ __launch_bounds__(512, 2) void attn_kernel(
    const short* __restrict__ Q, const short* __restrict__ K,
    const short* __restrict__ Vt, const float* __restrict__ x,
    float* __restrict__ out)
{
    extern __shared__ __align__(16) char smem[];   // 132096 B
    const int lin = blockIdx.x;
    const int b   = lin & 7;            // XCD swizzle: one b per XCD
    const int q0  = (lin >> 3) * 128;
    const int t    = threadIdx.x;
    const int w    = t >> 6;
    const int lane = t & 63;
    const int q    = lane & 31;         // this lane's q column
    const int hi   = lane >> 5;
    const int half = w >> 2;            // kv half: rows half*2048 .. +2047
    const int ww   = w & 3;             // q strip (q0 + ww*32 ..)

    const size_t bSD = (size_t)b * S_ * D_;

    // Q fragments: qf[c][j] = Q[q0+ww*32+q][c*16 + hi*8 + j]
    short8 qf[8];
    {
        const short* Qrow = Q + bSD + (size_t)(q0 + ww * 32 + q) * D_ + hi * 8;
        #pragma unroll
        for (int c = 0; c < 8; ++c)
            qf[c] = *(const short8*)(Qrow + c * 16);
    }

    f32x16 o[4];
    #pragma unroll
    for (int dt = 0; dt < 4; ++dt)
        #pragma unroll
        for (int i = 0; i < 16; ++i) o[dt][i] = 0.f;
    float m = -1e30f, lsum = 0.f;

    const short* Kb = K + bSD;
    const short* Vb = Vt + (size_t)b * D_ * S_;
    const int kvbase = half * 2048;

    char* const Kpriv = smem + w * 16384;   // this wave's private 16KB

    // DMA-stage one 32-kv K tile (8KB) into this wave's buffer `buf`.
    // LDS dest linear; global src pre-swizzled: phys 16B-chunk c of row r
    // holds logical chunk c^(r&7).
    auto stage = [&](int kt, int buf) {
        const short* Kg = Kb + (size_t)(kvbase + kt * 32) * D_;
        char* Kd = Kpriv + buf * 8192;
        #pragma unroll
        for (int i = 0; i < 8; ++i) {        // 1KB chunk: rows 4i..4i+3
            int r = i * 4 + (lane >> 4);
            gload16(Kg + r * D_ + (((lane & 15) ^ (r & 7)) * 8), Kd + i * 1024);
        }
    };

    stage(0, 0);
    asm volatile("s_waitcnt vmcnt(0)" ::: "memory");   // buf0 ready (own loads)
    int cur = 0;

    for (int kt = 0; kt < 64; ++kt) {
        if (kt + 1 < 64) stage(kt + 1, cur ^ 1);   // DMA overlaps compute

        const char* Kh = Kpriv + cur * 8192;

        // ---- S^T = K Q^T : acc[r] = S[k = (r&3)+8*(r>>2)+4*hi][q] ----
        f32x16 acc;
        #pragma unroll
        for (int i = 0; i < 16; ++i) acc[i] = 0.f;
        __builtin_amdgcn_s_setprio(1);
        #pragma unroll
        for (int c = 0; c < 8; ++c) {
            short8 kf = *(const short8*)(Kh + q * 256
                          + (((c * 2 + hi) ^ (q & 7)) * 16));
            acc = __builtin_amdgcn_mfma_f32_32x32x16_bf16(kf, qf[c], acc, 0, 0, 0);
        }
        __builtin_amdgcn_s_setprio(0);

        // ---- lane-local online softmax (exp2 domain), defer-max (T13) ----
        float t0 = fmaxf(acc[0],  acc[1]),  t1 = fmaxf(acc[2],  acc[3]);
        float t2 = fmaxf(acc[4],  acc[5]),  t3 = fmaxf(acc[6],  acc[7]);
        float t4 = fmaxf(acc[8],  acc[9]),  t5 = fmaxf(acc[10], acc[11]);
        float t6 = fmaxf(acc[12], acc[13]), t7 = fmaxf(acc[14], acc[15]);
        float ta = fmaxf(fmaxf(t0, t1), t2);
        float tb = fmaxf(fmaxf(t3, t4), t5);
        float tc = fmaxf(t6, t7);
        float tm = fmaxf(fmaxf(ta, tb), tc);
        tm = fmaxf(tm, __shfl_xor(tm, 32));
        if (!__all(tm <= m + 8.f)) {
            float mn   = fmaxf(m, tm);
            float corr = EXP2F(m - mn);
            m = mn; lsum *= corr;
            #pragma unroll
            for (int dt = 0; dt < 4; ++dt)
                #pragma unroll
                for (int r = 0; r < 16; ++r) o[dt][r] *= corr;
        }
        #pragma unroll
        for (int r = 0; r < 16; ++r) acc[r] = EXP2F(acc[r] - m);
        float s0 = (acc[0] + acc[1]) + (acc[2] + acc[3]);
        float s1 = (acc[4] + acc[5]) + (acc[6] + acc[7]);
        float s2 = (acc[8] + acc[9]) + (acc[10] + acc[11]);
        float s3 = (acc[12] + acc[13]) + (acc[14] + acc[15]);
        float ps = (s0 + s1) + (s2 + s3);
        ps += __shfl_xor(ps, 32);
        lsum += ps;

        // ---- P -> bf16 PV B-fragments, in-register via permlane32_swap ----
        // W0..W3 are distinct SSA defs -> no register-coalescing hazard.
        short8 pf[2];
        #pragma unroll
        for (int kc = 0; kc < 2; ++kc) {
            int c1 = kc * 8;
            uint W0 = cvtpk(acc[c1 + 0], acc[c1 + 1]);   // k: 4hi+{0,1}
            uint W1 = cvtpk(acc[c1 + 2], acc[c1 + 3]);   // k: 4hi+{2,3}
            uint W2 = cvtpk(acc[c1 + 4], acc[c1 + 5]);   // k: 8+4hi+{0,1}
            uint W3 = cvtpk(acc[c1 + 6], acc[c1 + 7]);   // k: 8+4hi+{2,3}
            asm("v_permlane32_swap_b32 %0, %1" : "+v"(W0), "+v"(W2));
            asm("v_permlane32_swap_b32 %0, %1" : "+v"(W1), "+v"(W3));
            uint4v pw;
            pw.x = W0;   // k 8hi+{0,1}
            pw.y = W1;   // k 8hi+{2,3}
            pw.z = W2;   // k 8hi+{4,5}
            pw.w = W3;   // k 8hi+{6,7}
            pf[kc] = *reinterpret_cast<short8*>(&pw);
        }

        // ---- O^T += V^T P^T  (V fragments direct from global / L2) ----
        const short* Vg = Vb + kvbase + kt * 32 + hi * 8;
        __builtin_amdgcn_s_setprio(1);
        #pragma unroll
        for (int kc = 0; kc < 2; ++kc)
            #pragma unroll
            for (int dt = 0; dt < 4; ++dt) {
                short8 vf = *(const short8*)(Vg + (size_t)(dt * 32 + q) * S_
                                             + kc * 16);
                o[dt] = __builtin_amdgcn_mfma_f32_32x32x16_bf16(vf, pf[kc], o[dt], 0, 0, 0);
            }
        __builtin_amdgcn_s_setprio(0);

        // Drain own K-DMA for buf[cur^1] before next iter ds_reads it.
        // ("memory" clobber orders the following ds_read, a memory op.)
        asm volatile("s_waitcnt vmcnt(0)" ::: "memory");
        cur ^= 1;
    }

    // ---- merge halves through LDS, residual-fused transposed writeout ----
    __syncthreads();                      // all waves done with private loops
    float2* ml = (float2*)(smem + 131072);
    if (half == 1) {
        float* obuf = (float*)(smem + (4 + ww) * 16384);   // own dead K region
        #pragma unroll
        for (int dt = 0; dt < 4; ++dt)
            #pragma unroll
            for (int r = 0; r < 16; ++r) {
                int dl = dt * 32 + (r & 3) + 8 * (r >> 2) + 4 * hi;
                obuf[dl * 32 + q] = o[dt][r];
            }
        if (hi == 0) {
            float2 v2; v2.x = m; v2.y = lsum;
            ml[ww * 32 + q] = v2;
        }
    }
    __syncthreads();
    if (half == 0) {
        const float* obuf = (const float*)(smem + (4 + ww) * 16384);
        float2 p = ml[ww * 32 + q];
        float m2 = p.x, l2 = p.y;
        float M  = fmaxf(m, m2);
        float c1 = EXP2F(m - M), c2 = EXP2F(m2 - M);
        float inv = 1.0f / (lsum * c1 + l2 * c2);
        const float* xb = x   + (size_t)b * D_ * S_;
        float*       ob = out + (size_t)b * D_ * S_;
        int s = q0 + ww * 32 + q;
        #pragma unroll
        for (int dt = 0; dt < 4; ++dt)
            #pragma unroll
            for (int r = 0; r < 16; ++r) {
                int dl = dt * 32 + (r & 3) + 8 * (r >> 2) + 4 * hi;
                float val = (o[dt][r] * c1 + obuf[dl * 32 + q] * c2) * inv;
                size_t g = (size_t)dl * S_ + s;
                ob[g] = xb[g] + val;
            }
    }
}

extern "C" void kernel_launch(void* const* d_in, const int* in_sizes, int n_in,
                              void* d_out, int out_size, void* d_ws, size_t ws_size,
                              hipStream_t stream) {
    const float* x  = (const float*)d_in[0];
    const float* Wq = (const float*)d_in[1];
    const float* bq = (const float*)d_in[2];
    const float* Wk = (const float*)d_in[3];
    const float* bk = (const float*)d_in[4];
    const float* Wv = (const float*)d_in[5];
    const float* bv = (const float*)d_in[6];
    float* out = (float*)d_out;

    size_t n = (size_t)B_ * S_ * D_;
    short* Qw = (short*)d_ws;
    short* Kw = Qw + n;
    short* Vw = Kw + n;
    short* Wf = (short*)d_out;   // scratch at head of d_out; fully overwritten

    wpack_kernel<<<24, 256, 0, stream>>>(Wq, Wk, Wv, Wf);

    dim3 grid(S_ / 64, B_);
    qkv_kernel<<<grid, 256, 0, stream>>>(x, Wf, bq, bk, bv, Qw, Kw, Vw);

    int smemB = 132096;
    (void)hipFuncSetAttribute((const void*)attn_kernel,
                              hipFuncAttributeMaxDynamicSharedMemorySize, smemB);
    attn_kernel<<<256, 512, smemB, stream>>>(Qw, Kw, Vw, x, out);
}

// Round 4
// 123.786 us; speedup vs baseline: 2.1701x; 1.7360x over previous
//
#include <hip/hip_runtime.h>
#include <hip/hip_bf16.h>

#define B_ 8
#define D_ 128
#define S_ 4096

typedef short short8 __attribute__((ext_vector_type(8)));
typedef float f32x4  __attribute__((ext_vector_type(4)));
typedef float f32x16 __attribute__((ext_vector_type(16)));
typedef unsigned int uint;
typedef uint uint4v __attribute__((ext_vector_type(4)));

#define EXP2F(x) exp2f(x)

__device__ __forceinline__ short f2bf(float f) {
    __hip_bfloat16 h = __float2bfloat16(f);
    return *reinterpret_cast<short*>(&h);
}

// pack two f32 -> one u32 of 2 bf16 (elem0 = lo word)
__device__ __forceinline__ uint cvtpk(float lo, float hi) {
    uint r;
    asm("v_cvt_pk_bf16_f32 %0, %1, %2" : "=v"(r) : "v"(lo), "v"(hi));
    return r;
}

// async global->LDS DMA, 16B/lane; LDS dest = wave-uniform base + lane*16
__device__ __forceinline__ void gload16(const void* g, void* l) {
    __builtin_amdgcn_global_load_lds(
        (const __attribute__((address_space(1))) void*)g,
        (__attribute__((address_space(3))) void*)l, 16, 0, 0);
}

// ---------------------------------------------------------------------------
// Kernel 0: pack Wq/Wk/Wv into bf16 MFMA fragments (16x16x32 layout for qkv).
// ---------------------------------------------------------------------------
__global__ __launch_bounds__(256) void wpack_kernel(
    const float* __restrict__ Wq, const float* __restrict__ Wk,
    const float* __restrict__ Wv, short* __restrict__ Wf)
{
    int g = blockIdx.x * 256 + threadIdx.x;      // 0..6143
    int lane = g & 63, kc = (g >> 6) & 3, n = (g >> 8) & 7, wm = g >> 11;
    const float* W = (wm == 0) ? Wq : (wm == 1) ? Wk : Wv;
    int row = n * 16 + (lane & 15);
    int col = kc * 32 + (lane >> 4) * 8;
    short8 o;
    #pragma unroll
    for (int j = 0; j < 8; ++j) o[j] = f2bf(W[row * 128 + col + j]);
    *((short8*)Wf + g) = o;
}

// ---------------------------------------------------------------------------
// Kernel 1: QKV projection via bf16 MFMA (16x16x32), unchanged.
// Q: (B,S,D) bf16 scaled by log2(e)/sqrt(D). K: (B,S,D). V: (B,D,S).
// ---------------------------------------------------------------------------
__global__ __launch_bounds__(256) void qkv_kernel(
    const float* __restrict__ x, const short* __restrict__ Wf,
    const float* __restrict__ bq, const float* __restrict__ bk,
    const float* __restrict__ bv,
    short* __restrict__ Qo, short* __restrict__ Ko, short* __restrict__ Vo)
{
    __shared__ float xt[64 * 132];
    const int b  = blockIdx.y;
    const int s0 = blockIdx.x * 64;
    const int t  = threadIdx.x;
    const int w    = t >> 6;
    const int lane = t & 63;
    const int lr   = lane & 15;
    const int lg   = lane >> 4;

    const float* xb = x + (size_t)b * D_ * S_;
    #pragma unroll
    for (int it = 0; it < 32; ++it) {
        int d = it * 4 + (t >> 6);
        int s = t & 63;
        xt[s * 132 + d] = xb[(size_t)d * S_ + s0 + s];
    }
    __syncthreads();

    short8 xtf[4];
    {
        const float* base = &xt[(w * 16 + lr) * 132 + lg * 8];
        #pragma unroll
        for (int kc = 0; kc < 4; ++kc) {
            float4 a = *(const float4*)(base + kc * 32);
            float4 c = *(const float4*)(base + kc * 32 + 4);
            short8 f;
            f[0] = f2bf(a.x); f[1] = f2bf(a.y); f[2] = f2bf(a.z); f[3] = f2bf(a.w);
            f[4] = f2bf(c.x); f[5] = f2bf(c.y); f[6] = f2bf(c.z); f[7] = f2bf(c.w);
            xtf[kc] = f;
        }
    }

    const float qs = 0.08838834764831845f * 1.4426950408889634f;
    const short8* W8 = (const short8*)Wf;
    const size_t bSD = (size_t)b * S_ * D_;
    const size_t bDS = (size_t)b * D_ * S_;

    #pragma unroll
    for (int n = 0; n < 8; ++n) {
        f32x4 aq = (f32x4){0.f, 0.f, 0.f, 0.f};
        f32x4 ak = (f32x4){0.f, 0.f, 0.f, 0.f};
        f32x4 av = (f32x4){0.f, 0.f, 0.f, 0.f};
        #pragma unroll
        for (int kc = 0; kc < 4; ++kc) {
            short8 wq = W8[(      n * 4 + kc) * 64 + lane];
            short8 wk = W8[(32  + n * 4 + kc) * 64 + lane];
            short8 wv = W8[(64  + n * 4 + kc) * 64 + lane];
            aq = __builtin_amdgcn_mfma_f32_16x16x32_bf16(xtf[kc], wq, aq, 0, 0, 0);
            ak = __builtin_amdgcn_mfma_f32_16x16x32_bf16(xtf[kc], wk, ak, 0, 0, 0);
            av = __builtin_amdgcn_mfma_f32_16x16x32_bf16(wv, xtf[kc], av, 0, 0, 0);
        }
        int e = n * 16 + lr;
        float bqe = bq[e], bke = bk[e];
        #pragma unroll
        for (int r = 0; r < 4; ++r) {
            size_t off = (bSD + (size_t)(s0 + w * 16 + lg * 4 + r) * D_) + e;
            Qo[off] = f2bf((aq[r] + bqe) * qs);
            Ko[off] = f2bf(ak[r] + bke);
        }
        #pragma unroll
        for (int r = 0; r < 4; ++r) {
            int ev = n * 16 + lg * 4 + r;
            Vo[bDS + (size_t)ev * S_ + s0 + w * 16 + lr] = f2bf(av[r] + bv[ev]);
        }
    }
}

// ---------------------------------------------------------------------------
// Kernel 2: flash attention, R0 structure + T15 software pipeline.
// 256 blocks x 512 threads = 2 KV-halves x 4 q-strips (128 q/block),
// 64-kv tiles, K AND V staged in LDS via global_load_lds (coalesced DMA +
// XOR-swizzled content; R3 proved direct-global V is uncoalesced poison).
// Pipeline: QK(t+1) -> accB is issued between softmax-part1(t) and the
// branch-free part2(t) {exp, sums, pack, PV}, so each wave's dependent
// MFMA chain and its big VALU block interleave in one scheduling region.
// K double-buffer is phase-shifted one tile ahead of V's.
// C/D layout (m74/m101): col=lane&31, row=(reg&3)+8*(reg>>2)+4*(lane>>5).
// ---------------------------------------------------------------------------
__global__ __launch_bounds__(512, 2) void attn_kernel(
    const short* __restrict__ Q, const short* __restrict__ K,
    const short* __restrict__ Vt, const float* __restrict__ x,
    float* __restrict__ out)
{
    extern __shared__ __align__(16) char smem[];   // 131072 B
    const int lin = blockIdx.x;
    const int b   = lin & 7;            // XCD swizzle: one b per XCD
    const int q0  = (lin >> 3) * 128;
    const int tid  = threadIdx.x;
    const int w    = tid >> 6;
    const int lane = tid & 63;
    const int q    = lane & 31;         // this lane's q column
    const int hi   = lane >> 5;
    const int half = w >> 2;            // KV half: tiles half*32 .. +31
    const int ww   = w & 3;             // q strip (q0 + ww*32 ..)

    const size_t bSD = (size_t)b * S_ * D_;

    // Q fragments: qf[c][j] = Q[q0+ww*32+q][c*16 + hi*8 + j]
    short8 qf[8];
    {
        const short* Qrow = Q + bSD + (size_t)(q0 + ww * 32 + q) * D_ + hi * 8;
        #pragma unroll
        for (int c = 0; c < 8; ++c)
            qf[c] = *(const short8*)(Qrow + c * 16);
    }

    f32x16 o[4];
    #pragma unroll
    for (int dt = 0; dt < 4; ++dt)
        #pragma unroll
        for (int i = 0; i < 16; ++i) o[dt][i] = 0.f;
    float m = -1e30f, lsum = 0.f;

    const short* Kb = K + bSD;
    const short* Vb = Vt + (size_t)b * D_ * S_;
    const int ktbase = half * 32;

    // Per-half LDS: K dbuf 2x16KB, V dbuf 2x16KB.
    char* const Kd0 = smem + half * 65536;
    char* const Kd1 = Kd0 + 16384;
    char* const Vd0 = Kd0 + 32768;
    char* const Vd1 = Vd0 + 16384;

    // DMA staging (linear LDS dest; global src pre-swizzled: phys 16B-chunk c
    // of row r holds logical chunk c^(r&7)).
    auto stageK = [&](int kt, char* Kd) {
        const short* Kg = Kb + (size_t)(ktbase + kt) * 64 * D_;
        #pragma unroll
        for (int i = 0; i < 4; ++i) {
            int ki = ww * 4 + i;                 // 1KB chunk: rows 4ki..4ki+3
            int r  = ki * 4 + (lane >> 4);
            gload16(Kg + r * D_ + (((lane & 15) ^ (r & 7)) * 8), Kd + ki * 1024);
        }
    };
    auto stageV = [&](int kt, char* Vd) {
        const short* Vg = Vb + (size_t)(ktbase + kt) * 64;
        #pragma unroll
        for (int i = 0; i < 4; ++i) {
            int vi = ww * 4 + i;                 // 1KB chunk: rows 8vi..8vi+7
            int r  = vi * 8 + (lane >> 3);
            gload16(Vg + (size_t)r * S_ + (((lane & 7) ^ (lane >> 3)) * 8),
                    Vd + vi * 1024);
        }
    };

    // S^T = K Q^T : a{0,1}[r] = S[k = n*32+(r&3)+8*(r>>2)+4*hi][q]
    auto qkrun = [&](const char* Kh, f32x16& a0, f32x16& a1) {
        #pragma unroll
        for (int i = 0; i < 16; ++i) { a0[i] = 0.f; a1[i] = 0.f; }
        __builtin_amdgcn_s_setprio(1);
        #pragma unroll
        for (int c = 0; c < 8; ++c) {
            int co = ((c * 2 + hi) ^ (q & 7)) * 16;
            short8 k0 = *(const short8*)(Kh + q * 256 + co);
            short8 k1 = *(const short8*)(Kh + (32 + q) * 256 + co);
            a0 = __builtin_amdgcn_mfma_f32_32x32x16_bf16(k0, qf[c], a0, 0, 0, 0);
            a1 = __builtin_amdgcn_mfma_f32_32x32x16_bf16(k1, qf[c], a1, 0, 0, 0);
        }
        __builtin_amdgcn_s_setprio(0);
    };

    // One pipelined tile body. Consumes accIn (tile t scores), runs QK(t+1)
    // into accOut between softmax part1 and the branch-free part2.
    auto body = [&](int t, char* KstD, char* VstD, const char* Krd,
                    const char* Vrd, f32x16& iA0, f32x16& iA1,
                    f32x16& oB0, f32x16& oB1) {
        if (t + 2 < 32) stageK(t + 2, KstD);
        if (t + 1 < 32) stageV(t + 1, VstD);

        // ---- part1: tile max + T13 defer-max gate (branchy, small) ----
        float x0 = fmaxf(fmaxf(iA0[0],  iA0[1]),  fmaxf(iA0[2],  iA0[3]));
        float x1 = fmaxf(fmaxf(iA0[4],  iA0[5]),  fmaxf(iA0[6],  iA0[7]));
        float x2 = fmaxf(fmaxf(iA0[8],  iA0[9]),  fmaxf(iA0[10], iA0[11]));
        float x3 = fmaxf(fmaxf(iA0[12], iA0[13]), fmaxf(iA0[14], iA0[15]));
        float x4 = fmaxf(fmaxf(iA1[0],  iA1[1]),  fmaxf(iA1[2],  iA1[3]));
        float x5 = fmaxf(fmaxf(iA1[4],  iA1[5]),  fmaxf(iA1[6],  iA1[7]));
        float x6 = fmaxf(fmaxf(iA1[8],  iA1[9]),  fmaxf(iA1[10], iA1[11]));
        float x7 = fmaxf(fmaxf(iA1[12], iA1[13]), fmaxf(iA1[14], iA1[15]));
        float tm = fmaxf(fmaxf(fmaxf(x0, x1), fmaxf(x2, x3)),
                         fmaxf(fmaxf(x4, x5), fmaxf(x6, x7)));
        tm = fmaxf(tm, __shfl_xor(tm, 32));
        if (!__all(tm <= m + 8.f)) {
            float mn   = fmaxf(m, tm);
            float corr = EXP2F(m - mn);
            m = mn; lsum *= corr;
            #pragma unroll
            for (int dt = 0; dt < 4; ++dt)
                #pragma unroll
                for (int r = 0; r < 16; ++r) o[dt][r] *= corr;
        }

        // ---- QK(t+1): independent MFMA chain, interleaves with part2 ----
        if (t + 1 < 32) qkrun(Krd, oB0, oB1);

        // ---- part2 (branch-free): exp, sums, pack, PV(t) ----
        #pragma unroll
        for (int r = 0; r < 16; ++r) iA0[r] = EXP2F(iA0[r] - m);
        #pragma unroll
        for (int r = 0; r < 16; ++r) iA1[r] = EXP2F(iA1[r] - m);
        float s0 = ((iA0[0]+iA0[1])+(iA0[2]+iA0[3]))
                 + ((iA0[4]+iA0[5])+(iA0[6]+iA0[7]));
        float s1 = ((iA0[8]+iA0[9])+(iA0[10]+iA0[11]))
                 + ((iA0[12]+iA0[13])+(iA0[14]+iA0[15]));
        float s2 = ((iA1[0]+iA1[1])+(iA1[2]+iA1[3]))
                 + ((iA1[4]+iA1[5])+(iA1[6]+iA1[7]));
        float s3 = ((iA1[8]+iA1[9])+(iA1[10]+iA1[11]))
                 + ((iA1[12]+iA1[13])+(iA1[14]+iA1[15]));
        float ps = (s0 + s1) + (s2 + s3);
        ps += __shfl_xor(ps, 32);
        lsum += ps;

        // P -> bf16 PV B-fragments (distinct SSA defs -> permlane safe)
        short8 pf[4];
        #pragma unroll
        for (int kc = 0; kc < 4; ++kc) {
            const f32x16& a = (kc < 2) ? iA0 : iA1;
            int c1 = (kc & 1) * 8;
            uint W0 = cvtpk(a[c1 + 0], a[c1 + 1]);
            uint W1 = cvtpk(a[c1 + 2], a[c1 + 3]);
            uint W2 = cvtpk(a[c1 + 4], a[c1 + 5]);
            uint W3 = cvtpk(a[c1 + 6], a[c1 + 7]);
            asm("v_permlane32_swap_b32 %0, %1" : "+v"(W0), "+v"(W2));
            asm("v_permlane32_swap_b32 %0, %1" : "+v"(W1), "+v"(W3));
            uint4v pw;
            pw.x = W0; pw.y = W1; pw.z = W2; pw.w = W3;
            pf[kc] = *reinterpret_cast<short8*>(&pw);
        }

        // O^T += V^T P^T
        __builtin_amdgcn_s_setprio(1);
        #pragma unroll
        for (int kc = 0; kc < 4; ++kc)
            #pragma unroll
            for (int dt = 0; dt < 4; ++dt) {
                int row = dt * 32 + q;
                short8 vf = *(const short8*)(Vrd + row * 128
                              + (((kc * 2 + hi) ^ (q & 7)) * 16));
                o[dt] = __builtin_amdgcn_mfma_f32_32x32x16_bf16(vf, pf[kc], o[dt], 0, 0, 0);
            }
        __builtin_amdgcn_s_setprio(0);

        __syncthreads();   // reads of tile t done + all staged DMA drained
    };

    // Prologue: K(0),V(0),K(1) staged; QK(0) computed; Kd0 freed for K(2).
    stageK(0, Kd0); stageV(0, Vd0); stageK(1, Kd1);
    __syncthreads();
    f32x16 aA0, aA1, aB0, aB1;
    #pragma unroll
    for (int i = 0; i < 16; ++i) { aB0[i] = 0.f; aB1[i] = 0.f; }
    qkrun(Kd0, aA0, aA1);
    __syncthreads();   // all waves' QK(0) reads done before K(2) DMA lands

    for (int t = 0; t < 32; t += 2) {
        body(t,     Kd0, Vd1, Kd1, Vd0, aA0, aA1, aB0, aB1);
        body(t + 1, Kd1, Vd0, Kd0, Vd1, aB0, aB1, aA0, aA1);
    }

    // ---- merge halves through LDS, residual-fused transposed writeout ----
    if (half == 1) {
        float* obuf = (float*)(smem + ww * 16384);
        #pragma unroll
        for (int dt = 0; dt < 4; ++dt)
            #pragma unroll
            for (int r = 0; r < 16; ++r) {
                int dl = dt * 32 + (r & 3) + 8 * (r >> 2) + 4 * hi;
                obuf[dl * 32 + q] = o[dt][r];
            }
        if (hi == 0) {
            float* ml = (float*)(smem + 65536 + ww * 256);
            ml[q * 2]     = m;
            ml[q * 2 + 1] = lsum;
        }
    }
    __syncthreads();
    if (half == 0) {
        const float* obuf = (const float*)(smem + ww * 16384);
        const float* ml   = (const float*)(smem + 65536 + ww * 256);
        float m2 = ml[q * 2], l2 = ml[q * 2 + 1];
        float M  = fmaxf(m, m2);
        float c1 = EXP2F(m - M), c2 = EXP2F(m2 - M);
        float inv = 1.0f / (lsum * c1 + l2 * c2);
        const float* xb = x   + (size_t)b * D_ * S_;
        float*       ob = out + (size_t)b * D_ * S_;
        int s = q0 + ww * 32 + q;
        #pragma unroll
        for (int dt = 0; dt < 4; ++dt)
            #pragma unroll
            for (int r = 0; r < 16; ++r) {
                int dl = dt * 32 + (r & 3) + 8 * (r >> 2) + 4 * hi;
                float val = (o[dt][r] * c1 + obuf[dl * 32 + q] * c2) * inv;
                size_t g = (size_t)dl * S_ + s;
                ob[g] = xb[g] + val;
            }
    }
}

extern "C" void kernel_launch(void* const* d_in, const int* in_sizes, int n_in,
                              void* d_out, int out_size, void* d_ws, size_t ws_size,
                              hipStream_t stream) {
    const float* x  = (const float*)d_in[0];
    const float* Wq = (const float*)d_in[1];
    const float* bq = (const float*)d_in[2];
    const float* Wk = (const float*)d_in[3];
    const float* bk = (const float*)d_in[4];
    const float* Wv = (const float*)d_in[5];
    const float* bv = (const float*)d_in[6];
    float* out = (float*)d_out;

    size_t n = (size_t)B_ * S_ * D_;
    short* Qw = (short*)d_ws;
    short* Kw = Qw + n;
    short* Vw = Kw + n;
    short* Wf = (short*)d_out;   // scratch at head of d_out; fully overwritten

    wpack_kernel<<<24, 256, 0, stream>>>(Wq, Wk, Wv, Wf);

    dim3 grid(S_ / 64, B_);
    qkv_kernel<<<grid, 256, 0, stream>>>(x, Wf, bq, bk, bv, Qw, Kw, Vw);

    int smemB = 131072;
    (void)hipFuncSetAttribute((const void*)attn_kernel,
                              hipFuncAttributeMaxDynamicSharedMemorySize, smemB);
    attn_kernel<<<256, 512, smemB, stream>>>(Qw, Kw, Vw, x, out);
}